// Round 1
// baseline (513.075 us; speedup 1.0000x reference)
//
#include <hip/hip_runtime.h>

#define N_Q 4096
#define N_O 4096
#define LAT 64
#define HEADS 4
#define HD 16
#define NCHUNK 16
#define OCHUNK 256

// ---------------- phase 1a: qc[q][j], oc[o][j] ----------------
__global__ __launch_bounds__(256) void prep_qo(
    const float* __restrict__ pos_obs, const float* __restrict__ pos_query,
    const float* __restrict__ W1, const float* __restrict__ b1,
    float* __restrict__ qc, float* __restrict__ oc)
{
    int gid = blockIdx.x * 256 + threadIdx.x;
    int row = gid >> 6, j = gid & 63;
    if (row < N_Q) {
        const float* pq = pos_query + row * 3;
        float acc = b1[j];
        #pragma unroll
        for (int p = 0; p < 3; ++p)
            acc = fmaf(pq[p], W1[p * LAT + j] + W1[(3 + p) * LAT + j], acc);
        qc[row * LAT + j] = acc;
    } else {
        int o = row - N_Q;
        const float* po = pos_obs + o * 3;
        float acc = 0.f;
        #pragma unroll
        for (int p = 0; p < 3; ++p)
            acc = fmaf(po[p], W1[(6 + p) * LAT + j] - W1[p * LAT + j], acc);
        oc[o * LAT + j] = acc;
    }
}

// ---------------- phase 1b: v[o][hd] = h_obs[o]@Wv + bv ----------------
__global__ __launch_bounds__(256) void prep_v(
    const float* __restrict__ h_obs, const float* __restrict__ Wv,
    const float* __restrict__ bv, float* __restrict__ vv)
{
    int gid = blockIdx.x * 256 + threadIdx.x;
    int o = gid >> 6, j = gid & 63;
    float acc = bv[j];
    #pragma unroll 8
    for (int k = 0; k < LAT; ++k)
        acc = fmaf(h_obs[o * LAT + k], Wv[k * LAT + j], acc);
    vv[o * LAT + j] = acc;
}

// ---------------- phase 2: per-(chunk, q-tile) attention ----------------
// block = 256 thr = 64 q (lane) x 4 o-groups. Each thread: online softmax over
// 64 o's; LDS combine across o-groups with rescale to the true chunk max
// (faithful to reference per-chunk-max semantics); write partial sums.
__global__ __launch_bounds__(256, 2) void attn_chunk(
    const float* __restrict__ pos_obs, const float* __restrict__ pos_query,
    const float* __restrict__ W1, const float* __restrict__ W2,
    const float* __restrict__ b2, const float* __restrict__ log_sigma,
    const float* __restrict__ qc, const float* __restrict__ oc,
    const float* __restrict__ vv, float* __restrict__ part)
{
    __shared__ float lm[4][64][HEADS];
    __shared__ float acc_s[64][68];

    const int chunk = blockIdx.x, qtile = blockIdx.y;
    const int tid = threadIdx.x;
    const int ql = tid & 63, og = tid >> 6;
    const int q = qtile * 64 + ql;

    const float sigma = __expf(log_sigma[0]) + 1e-6f;
    const float inv2s2 = 1.0f / (2.0f * sigma * sigma);

    // qc row -> registers (L1/L2-resident, once per thread)
    float qcr[LAT];
    {
        const float4* qp4 = (const float4*)(qc + (size_t)q * LAT);
        #pragma unroll
        for (int jj = 0; jj < LAT / 4; ++jj) {
            float4 t = qp4[jj];
            qcr[jj * 4 + 0] = t.x; qcr[jj * 4 + 1] = t.y;
            qcr[jj * 4 + 2] = t.z; qcr[jj * 4 + 3] = t.w;
        }
    }
    const float qp0 = pos_query[q * 3 + 0];
    const float qp1 = pos_query[q * 3 + 1];
    const float qp2 = pos_query[q * 3 + 2];

    float m[HEADS], den[HEADS], num[HEADS][HD];
    #pragma unroll
    for (int h = 0; h < HEADS; ++h) {
        m[h] = -1e30f; den[h] = 0.f;
        #pragma unroll
        for (int d = 0; d < HD; ++d) num[h][d] = 0.f;
    }

    int obase = chunk * OCHUNK + og * 64;
    obase = __builtin_amdgcn_readfirstlane(obase);  // wave-uniform -> s_load path
    const float* c9 = W1 + 9 * LAT;

    const float b2r0 = b2[0], b2r1 = b2[1], b2r2 = b2[2], b2r3 = b2[3];

    for (int oo = 0; oo < 64; ++oo) {
        const int o = obase + oo;
        const float op0 = pos_obs[o * 3 + 0];
        const float op1 = pos_obs[o * 3 + 1];
        const float op2 = pos_obs[o * 3 + 2];
        const float r0 = qp0 - op0, r1 = qp1 - op1, r2 = qp2 - op2;
        const float dist2 = fmaf(r0, r0, fmaf(r1, r1, r2 * r2));
        const float rbf = __expf(-dist2);

        float lg[HEADS];
        lg[0] = fmaf(-dist2, inv2s2, b2r0);
        lg[1] = fmaf(-dist2, inv2s2, b2r1);
        lg[2] = fmaf(-dist2, inv2s2, b2r2);
        lg[3] = fmaf(-dist2, inv2s2, b2r3);

        const float* ocp = oc + (size_t)o * LAT;
        #pragma unroll
        for (int j = 0; j < LAT; ++j) {
            float hp = fmaf(rbf, c9[j], qcr[j] + ocp[j]);
            hp = fmaxf(hp, 0.f);
            #pragma unroll
            for (int h = 0; h < HEADS; ++h)
                lg[h] = fmaf(hp, W2[j * HEADS + h], lg[h]);
        }

        const float* vp = vv + (size_t)o * LAT;
        #pragma unroll
        for (int h = 0; h < HEADS; ++h) {
            const float mn = fmaxf(m[h], lg[h]);
            const float sc = __expf(m[h] - mn);
            const float p  = __expf(lg[h] - mn);
            m[h] = mn;
            den[h] = fmaf(den[h], sc, p);
            #pragma unroll
            for (int d = 0; d < HD; ++d)
                num[h][d] = fmaf(num[h][d], sc, p * vp[h * HD + d]);
        }
    }

    // ---- combine the 4 o-groups at the true chunk max ----
    #pragma unroll
    for (int h = 0; h < HEADS; ++h) lm[og][ql][h] = m[h];
    __syncthreads();
    #pragma unroll
    for (int h = 0; h < HEADS; ++h) {
        const float mc = fmaxf(fmaxf(lm[0][ql][h], lm[1][ql][h]),
                               fmaxf(lm[2][ql][h], lm[3][ql][h]));
        const float sc = __expf(m[h] - mc);
        den[h] *= sc;
        #pragma unroll
        for (int d = 0; d < HD; ++d) num[h][d] *= sc;
    }
    // staged accumulation into LDS (og = 0..3 sequentially)
    for (int g = 0; g < 4; ++g) {
        if (og == g) {
            if (g == 0) {
                #pragma unroll
                for (int h = 0; h < HEADS; ++h) {
                    acc_s[ql][64 + h] = den[h];
                    #pragma unroll
                    for (int d = 0; d < HD; ++d) acc_s[ql][h * HD + d] = num[h][d];
                }
            } else {
                #pragma unroll
                for (int h = 0; h < HEADS; ++h) {
                    acc_s[ql][64 + h] += den[h];
                    #pragma unroll
                    for (int d = 0; d < HD; ++d) acc_s[ql][h * HD + d] += num[h][d];
                }
            }
        }
        __syncthreads();
    }
    // coalesced write of this (chunk, q-tile) partial region
    float* dst = part + (size_t)(chunk * N_Q + qtile * 64) * 68;
    for (int f = tid; f < 64 * 68; f += 256) {
        int qq = f / 68, e = f % 68;
        dst[(size_t)qq * 68 + e] = acc_s[qq][e];
    }
}

// ---------------- phase 3: sum chunk partials, divide ----------------
__global__ __launch_bounds__(256) void finalize_k(
    const float* __restrict__ part, float* __restrict__ out)
{
    int gid = blockIdx.x * 256 + threadIdx.x;
    int q = gid >> 6, e = gid & 63;
    int h = e >> 4;
    float ns = 0.f, ds = 0.f;
    #pragma unroll
    for (int c = 0; c < NCHUNK; ++c) {
        const float* row = part + (size_t)(c * N_Q + q) * 68;
        ns += row[e];
        ds += row[64 + h];
    }
    out[q * LAT + e] = ns / (ds + 1e-9f);
}

extern "C" void kernel_launch(void* const* d_in, const int* in_sizes, int n_in,
                              void* d_out, int out_size, void* d_ws, size_t ws_size,
                              hipStream_t stream) {
    const float* h_obs     = (const float*)d_in[0];
    const float* pos_obs   = (const float*)d_in[1];
    const float* pos_query = (const float*)d_in[2];
    const float* W1        = (const float*)d_in[3];
    const float* b1        = (const float*)d_in[4];
    const float* W2        = (const float*)d_in[5];
    const float* b2        = (const float*)d_in[6];
    const float* Wv        = (const float*)d_in[7];
    const float* bv        = (const float*)d_in[8];
    const float* log_sigma = (const float*)d_in[9];
    float* out = (float*)d_out;

    float* w   = (float*)d_ws;
    float* qc  = w;                       // 4096*64
    float* oc  = qc + N_Q * LAT;          // 4096*64
    float* vv  = oc + (size_t)N_O * LAT;  // 4096*64
    float* part = vv + (size_t)N_O * LAT; // 16*4096*68  (~17.8 MB)

    prep_qo<<<(N_Q + N_O) * LAT / 256, 256, 0, stream>>>(pos_obs, pos_query, W1, b1, qc, oc);
    prep_v<<<N_O * LAT / 256, 256, 0, stream>>>(h_obs, Wv, bv, vv);
    attn_chunk<<<dim3(NCHUNK, N_Q / 64), 256, 0, stream>>>(
        pos_obs, pos_query, W1, W2, b2, log_sigma, qc, oc, vv, part);
    finalize_k<<<N_Q * LAT / 256, 256, 0, stream>>>(part, out);
}

// Round 2
// 379.155 us; speedup vs baseline: 1.3532x; 1.3532x over previous
//
#include <hip/hip_runtime.h>

#define N_Q 4096
#define N_O 4096
#define LAT 64
#define HEADS 4
#define HD 16
#define NCHUNK 16
#define OCHUNK 256
#define L2E 1.4426950408889634f

// ---- fused prep: qc[q][j], oc[o][j], v[o][hd] ----
__global__ __launch_bounds__(256) void prep_all(
    const float* __restrict__ h_obs, const float* __restrict__ pos_obs,
    const float* __restrict__ pos_query,
    const float* __restrict__ W1, const float* __restrict__ b1,
    const float* __restrict__ Wv, const float* __restrict__ bv,
    float* __restrict__ qc, float* __restrict__ oc, float* __restrict__ vv)
{
    int gid = blockIdx.x * 256 + threadIdx.x;
    int row = gid >> 6, j = gid & 63;
    if (row < N_Q) {
        const float* pq = pos_query + row * 3;
        float acc = b1[j];
        #pragma unroll
        for (int p = 0; p < 3; ++p)
            acc = fmaf(pq[p], W1[p * LAT + j] + W1[(3 + p) * LAT + j], acc);
        qc[row * LAT + j] = acc;
    } else if (row < N_Q + N_O) {
        int o = row - N_Q;
        const float* po = pos_obs + o * 3;
        float acc = 0.f;
        #pragma unroll
        for (int p = 0; p < 3; ++p)
            acc = fmaf(po[p], W1[(6 + p) * LAT + j] - W1[p * LAT + j], acc);
        oc[o * LAT + j] = acc;
    } else {
        int o = row - N_Q - N_O;
        float acc = bv[j];
        #pragma unroll 8
        for (int k = 0; k < LAT; ++k)
            acc = fmaf(h_obs[o * LAT + k], Wv[k * LAT + j], acc);
        vv[o * LAT + j] = acc;
    }
}

// LDS layout (float words)
#define QCB 0        // 64*65 = 4160 used; region is 4352 (aliased as acc[64][68])
#define OCB 4352     // 4 waves * 16 o * 64 j = 4096
#define VVB 8448     // 4096
#define W2B 12544    // 64*4 = 256   (pre-scaled by log2e)
#define C9B 12800    // 64
#define LMB 12864    // 4*64*4 = 1024
#define SMEM_WORDS 13888  // 55.5 KB

__global__ __launch_bounds__(256, 2) void attn_chunk(
    const float* __restrict__ pos_obs, const float* __restrict__ pos_query,
    const float* __restrict__ W1, const float* __restrict__ W2,
    const float* __restrict__ b2, const float* __restrict__ log_sigma,
    const float* __restrict__ qc, const float* __restrict__ oc,
    const float* __restrict__ vv, float* __restrict__ part)
{
    __shared__ float smem[SMEM_WORDS];

    const int chunk = blockIdx.x, qtile = blockIdx.y;
    const int tid = threadIdx.x;
    const int ql = tid & 63, og = tid >> 6;
    const int q = qtile * 64 + ql;

    const float sigma = __expf(log_sigma[0]) + 1e-6f;
    const float inv2s2l = L2E / (2.0f * sigma * sigma);
    float b2l[HEADS];
    #pragma unroll
    for (int h = 0; h < HEADS; ++h) b2l[h] = b2[h] * L2E;

    // ---- block-wide staging: qc tile, W2 (x log2e), c9 ----
    for (int idx = tid; idx < 1024; idx += 256) {           // 64 rows x 16 float4
        int row = idx >> 4, c4 = idx & 15;
        float4 t = *(const float4*)(qc + ((size_t)(qtile * 64 + row)) * LAT + c4 * 4);
        int b = QCB + row * 65 + c4 * 4;
        smem[b] = t.x; smem[b + 1] = t.y; smem[b + 2] = t.z; smem[b + 3] = t.w;
    }
    if (tid < 64) {
        float4 t = *(const float4*)(W2 + tid * 4);
        float4 s; s.x = t.x * L2E; s.y = t.y * L2E; s.z = t.z * L2E; s.w = t.w * L2E;
        *(float4*)&smem[W2B + tid * 4] = s;
        smem[C9B + tid] = W1[9 * LAT + tid];
    }
    __syncthreads();

    const float qp0 = pos_query[q * 3 + 0];
    const float qp1 = pos_query[q * 3 + 1];
    const float qp2 = pos_query[q * 3 + 2];

    float m[HEADS], den[HEADS], num[HEADS][HD];
    #pragma unroll
    for (int h = 0; h < HEADS; ++h) {
        m[h] = -1e30f; den[h] = 0.f;
        #pragma unroll
        for (int d = 0; d < HD; ++d) num[h][d] = 0.f;
    }

    const int obase = chunk * OCHUNK + og * 64;

    for (int r = 0; r < 4; ++r) {
        // ---- wave-private restage of 16 o's of oc, vv ----
        const int oslice = obase + r * 16;
        const float4* osrc = (const float4*)(oc + (size_t)oslice * LAT);
        const float4* vsrc = (const float4*)(vv + (size_t)oslice * LAT);
        #pragma unroll
        for (int k = 0; k < 4; ++k) {
            *(float4*)&smem[OCB + og * 1024 + (ql + 64 * k) * 4] = osrc[ql + 64 * k];
            *(float4*)&smem[VVB + og * 1024 + (ql + 64 * k) * 4] = vsrc[ql + 64 * k];
        }

        for (int g = 0; g < 2; ++g) {
            const int lo0 = g * 8;
            // distances + rbf for 8 o's
            float d2[8], rbf[8];
            #pragma unroll
            for (int oi = 0; oi < 8; ++oi) {
                const float* po = pos_obs + (size_t)(oslice + lo0 + oi) * 3;
                float r0 = qp0 - po[0], r1 = qp1 - po[1], r2 = qp2 - po[2];
                d2[oi] = fmaf(r0, r0, fmaf(r1, r1, r2 * r2));
                rbf[oi] = __expf(-d2[oi]);
            }
            float lg[8][HEADS];
            #pragma unroll
            for (int oi = 0; oi < 8; ++oi)
                #pragma unroll
                for (int h = 0; h < HEADS; ++h)
                    lg[oi][h] = fmaf(-d2[oi], inv2s2l, b2l[h]);

            // ---- hidden layer: 64 j, 8 o's per pass ----
            #pragma unroll 4
            for (int j4 = 0; j4 < 16; ++j4) {
                float4 w2v[4];
                #pragma unroll
                for (int jj = 0; jj < 4; ++jj)
                    w2v[jj] = *(const float4*)&smem[W2B + (j4 * 4 + jj) * 4];
                float4 c9v = *(const float4*)&smem[C9B + j4 * 4];
                float qv[4];
                #pragma unroll
                for (int jj = 0; jj < 4; ++jj)
                    qv[jj] = smem[QCB + ql * 65 + j4 * 4 + jj];
                #pragma unroll
                for (int oi = 0; oi < 8; ++oi) {
                    float4 ocv = *(const float4*)&smem[OCB + og * 1024 + (lo0 + oi) * 64 + j4 * 4];
                    float hp;
                    hp = fmaf(rbf[oi], c9v.x, qv[0] + ocv.x); hp = fmaxf(hp, 0.f);
                    lg[oi][0] = fmaf(hp, w2v[0].x, lg[oi][0]);
                    lg[oi][1] = fmaf(hp, w2v[0].y, lg[oi][1]);
                    lg[oi][2] = fmaf(hp, w2v[0].z, lg[oi][2]);
                    lg[oi][3] = fmaf(hp, w2v[0].w, lg[oi][3]);
                    hp = fmaf(rbf[oi], c9v.y, qv[1] + ocv.y); hp = fmaxf(hp, 0.f);
                    lg[oi][0] = fmaf(hp, w2v[1].x, lg[oi][0]);
                    lg[oi][1] = fmaf(hp, w2v[1].y, lg[oi][1]);
                    lg[oi][2] = fmaf(hp, w2v[1].z, lg[oi][2]);
                    lg[oi][3] = fmaf(hp, w2v[1].w, lg[oi][3]);
                    hp = fmaf(rbf[oi], c9v.z, qv[2] + ocv.z); hp = fmaxf(hp, 0.f);
                    lg[oi][0] = fmaf(hp, w2v[2].x, lg[oi][0]);
                    lg[oi][1] = fmaf(hp, w2v[2].y, lg[oi][1]);
                    lg[oi][2] = fmaf(hp, w2v[2].z, lg[oi][2]);
                    lg[oi][3] = fmaf(hp, w2v[2].w, lg[oi][3]);
                    hp = fmaf(rbf[oi], c9v.w, qv[3] + ocv.w); hp = fmaxf(hp, 0.f);
                    lg[oi][0] = fmaf(hp, w2v[3].x, lg[oi][0]);
                    lg[oi][1] = fmaf(hp, w2v[3].y, lg[oi][1]);
                    lg[oi][2] = fmaf(hp, w2v[3].z, lg[oi][2]);
                    lg[oi][3] = fmaf(hp, w2v[3].w, lg[oi][3]);
                }
            }

            // ---- online softmax + PV over the 8 o's (sequential) ----
            #pragma unroll
            for (int oi = 0; oi < 8; ++oi) {
                const int lo = lo0 + oi;
                const int vb = VVB + og * 1024 + lo * 64;
                bool up = (lg[oi][0] > m[0]) || (lg[oi][1] > m[1]) ||
                          (lg[oi][2] > m[2]) || (lg[oi][3] > m[3]);
                if (!__any(up)) {
                    // fast path: max unchanged for every lane in the wave
                    #pragma unroll
                    for (int h = 0; h < HEADS; ++h) {
                        float p = exp2f(lg[oi][h] - m[h]);
                        den[h] += p;
                        const float4* vp = (const float4*)&smem[vb + h * HD];
                        #pragma unroll
                        for (int d4 = 0; d4 < 4; ++d4) {
                            float4 t = vp[d4];
                            num[h][d4 * 4 + 0] = fmaf(p, t.x, num[h][d4 * 4 + 0]);
                            num[h][d4 * 4 + 1] = fmaf(p, t.y, num[h][d4 * 4 + 1]);
                            num[h][d4 * 4 + 2] = fmaf(p, t.z, num[h][d4 * 4 + 2]);
                            num[h][d4 * 4 + 3] = fmaf(p, t.w, num[h][d4 * 4 + 3]);
                        }
                    }
                } else {
                    #pragma unroll
                    for (int h = 0; h < HEADS; ++h) {
                        float nm = fmaxf(m[h], lg[oi][h]);
                        float sc = exp2f(m[h] - nm);
                        float p  = exp2f(lg[oi][h] - nm);
                        m[h] = nm;
                        den[h] = fmaf(den[h], sc, p);
                        const float4* vp = (const float4*)&smem[vb + h * HD];
                        #pragma unroll
                        for (int d4 = 0; d4 < 4; ++d4) {
                            float4 t = vp[d4];
                            num[h][d4 * 4 + 0] = fmaf(num[h][d4 * 4 + 0], sc, p * t.x);
                            num[h][d4 * 4 + 1] = fmaf(num[h][d4 * 4 + 1], sc, p * t.y);
                            num[h][d4 * 4 + 2] = fmaf(num[h][d4 * 4 + 2], sc, p * t.z);
                            num[h][d4 * 4 + 3] = fmaf(num[h][d4 * 4 + 3], sc, p * t.w);
                        }
                    }
                }
            }
        }
    }

    // ---- combine the 4 o-groups at the true chunk max ----
    #pragma unroll
    for (int h = 0; h < HEADS; ++h) smem[LMB + (og * 64 + ql) * 4 + h] = m[h];
    __syncthreads();
    #pragma unroll
    for (int h = 0; h < HEADS; ++h) {
        const float mc = fmaxf(
            fmaxf(smem[LMB + (0 * 64 + ql) * 4 + h], smem[LMB + (1 * 64 + ql) * 4 + h]),
            fmaxf(smem[LMB + (2 * 64 + ql) * 4 + h], smem[LMB + (3 * 64 + ql) * 4 + h]));
        const float sc = exp2f(m[h] - mc);
        den[h] *= sc;
        #pragma unroll
        for (int d = 0; d < HD; ++d) num[h][d] *= sc;
    }
    // staged accumulation into acc region (aliases qc region; all qc reads done)
    for (int g = 0; g < 4; ++g) {
        if (og == g) {
            if (g == 0) {
                #pragma unroll
                for (int h = 0; h < HEADS; ++h) {
                    smem[QCB + ql * 68 + 64 + h] = den[h];
                    #pragma unroll
                    for (int d = 0; d < HD; ++d) smem[QCB + ql * 68 + h * HD + d] = num[h][d];
                }
            } else {
                #pragma unroll
                for (int h = 0; h < HEADS; ++h) {
                    smem[QCB + ql * 68 + 64 + h] += den[h];
                    #pragma unroll
                    for (int d = 0; d < HD; ++d) smem[QCB + ql * 68 + h * HD + d] += num[h][d];
                }
            }
        }
        __syncthreads();
    }
    float* dst = part + (size_t)(chunk * N_Q + qtile * 64) * 68;
    for (int f = tid; f < 64 * 68; f += 256) {
        int qq = f / 68, e = f % 68;
        dst[(size_t)qq * 68 + e] = smem[QCB + qq * 68 + e];
    }
}

// ---- finalize: sum chunk partials, divide ----
__global__ __launch_bounds__(256) void finalize_k(
    const float* __restrict__ part, float* __restrict__ out)
{
    int gid = blockIdx.x * 256 + threadIdx.x;
    int q = gid >> 6, e = gid & 63;
    int h = e >> 4;
    float ns = 0.f, ds = 0.f;
    #pragma unroll
    for (int c = 0; c < NCHUNK; ++c) {
        const float* row = part + (size_t)(c * N_Q + q) * 68;
        ns += row[e];
        ds += row[64 + h];
    }
    out[q * LAT + e] = ns / (ds + 1e-9f);
}

extern "C" void kernel_launch(void* const* d_in, const int* in_sizes, int n_in,
                              void* d_out, int out_size, void* d_ws, size_t ws_size,
                              hipStream_t stream) {
    const float* h_obs     = (const float*)d_in[0];
    const float* pos_obs   = (const float*)d_in[1];
    const float* pos_query = (const float*)d_in[2];
    const float* W1        = (const float*)d_in[3];
    const float* b1        = (const float*)d_in[4];
    const float* W2        = (const float*)d_in[5];
    const float* b2        = (const float*)d_in[6];
    const float* Wv        = (const float*)d_in[7];
    const float* bv        = (const float*)d_in[8];
    const float* log_sigma = (const float*)d_in[9];
    float* out = (float*)d_out;

    float* w   = (float*)d_ws;
    float* qc  = w;                       // 4096*64
    float* oc  = qc + N_Q * LAT;          // 4096*64
    float* vv  = oc + (size_t)N_O * LAT;  // 4096*64
    float* part = vv + (size_t)N_O * LAT; // 16*4096*68

    prep_all<<<(N_Q + N_O + N_O) * LAT / 256, 256, 0, stream>>>(
        h_obs, pos_obs, pos_query, W1, b1, Wv, bv, qc, oc, vv);
    attn_chunk<<<dim3(NCHUNK, N_Q / 64), 256, 0, stream>>>(
        pos_obs, pos_query, W1, W2, b2, log_sigma, qc, oc, vv, part);
    finalize_k<<<N_Q * LAT / 256, 256, 0, stream>>>(part, out);
}

// Round 3
// 350.194 us; speedup vs baseline: 1.4651x; 1.0827x over previous
//
#include <hip/hip_runtime.h>

#define N_Q 4096
#define N_O 4096
#define LAT 64
#define HEADS 4
#define HD 16
#define NCHUNK 16
#define OCHUNK 256
#define L2E 1.4426950408889634f

typedef float f2 __attribute__((ext_vector_type(2)));
typedef float f4 __attribute__((ext_vector_type(4)));

// ---- fused prep: qc[q][j], oc[o][j], v[o][hd] ----
__global__ __launch_bounds__(256) void prep_all(
    const float* __restrict__ h_obs, const float* __restrict__ pos_obs,
    const float* __restrict__ pos_query,
    const float* __restrict__ W1, const float* __restrict__ b1,
    const float* __restrict__ Wv, const float* __restrict__ bv,
    float* __restrict__ qc, float* __restrict__ oc, float* __restrict__ vv)
{
    int gid = blockIdx.x * 256 + threadIdx.x;
    int row = gid >> 6, j = gid & 63;
    if (row < N_Q) {
        const float* pq = pos_query + row * 3;
        float acc = b1[j];
        #pragma unroll
        for (int p = 0; p < 3; ++p)
            acc = fmaf(pq[p], W1[p * LAT + j] + W1[(3 + p) * LAT + j], acc);
        qc[row * LAT + j] = acc;
    } else if (row < N_Q + N_O) {
        int o = row - N_Q;
        const float* po = pos_obs + o * 3;
        float acc = 0.f;
        #pragma unroll
        for (int p = 0; p < 3; ++p)
            acc = fmaf(po[p], W1[(6 + p) * LAT + j] - W1[p * LAT + j], acc);
        oc[o * LAT + j] = acc;
    } else {
        int o = row - N_Q - N_O;
        float acc = bv[j];
        #pragma unroll 8
        for (int k = 0; k < LAT; ++k)
            acc = fmaf(h_obs[o * LAT + k], Wv[k * LAT + j], acc);
        vv[o * LAT + j] = acc;
    }
}

// LDS layout (float words)
#define QCB 0        // qc tile [64][66] = 4224; region 4352 (aliased as acc[64][68])
#define OCB 4352     // 4 waves * 8 o * 64 = 2048
#define VVB 6400     // 2048
#define W2B 8448     // 64*4 (x log2e)
#define C9B 8704     // 64
#define LMB 8768     // 4*64*4
#define SMEM_WORDS 9792  // 39168 B

__global__ __launch_bounds__(256, 2) void attn_chunk(
    const float* __restrict__ pos_obs, const float* __restrict__ pos_query,
    const float* __restrict__ W1, const float* __restrict__ W2,
    const float* __restrict__ b2, const float* __restrict__ log_sigma,
    const float* __restrict__ qc, const float* __restrict__ oc,
    const float* __restrict__ vv, float* __restrict__ part)
{
    __shared__ float smem[SMEM_WORDS];

    const int chunk = blockIdx.x, qtile = blockIdx.y;
    const int tid = threadIdx.x;
    const int ql = tid & 63;
    const int og = __builtin_amdgcn_readfirstlane(tid >> 6);  // wave-uniform
    const int q = qtile * 64 + ql;

    const float sigma = __expf(log_sigma[0]) + 1e-6f;
    const float inv2s2l = L2E / (2.0f * sigma * sigma);
    const float b2l0 = b2[0] * L2E, b2l1 = b2[1] * L2E;
    const float b2l2 = b2[2] * L2E, b2l3 = b2[3] * L2E;

    // ---- block staging: qc tile [64][66], W2 (x log2e), c9 ----
    for (int idx = tid; idx < 1024; idx += 256) {
        int row = idx >> 4, c4 = idx & 15;
        float4 t = *(const float4*)(qc + ((size_t)(qtile * 64 + row)) * LAT + c4 * 4);
        int b = QCB + row * 66 + c4 * 4;
        smem[b] = t.x; smem[b + 1] = t.y; smem[b + 2] = t.z; smem[b + 3] = t.w;
    }
    if (tid < 64) {
        float4 t = *(const float4*)(W2 + tid * 4);
        float4 s; s.x = t.x * L2E; s.y = t.y * L2E; s.z = t.z * L2E; s.w = t.w * L2E;
        *(float4*)&smem[W2B + tid * 4] = s;
        smem[C9B + tid] = W1[9 * LAT + tid];
    }
    __syncthreads();

    const float qp0 = pos_query[q * 3 + 0];
    const float qp1 = pos_query[q * 3 + 1];
    const float qp2 = pos_query[q * 3 + 2];

    float m[HEADS], den[HEADS];
    f2 num2[HEADS][8];
    #pragma unroll
    for (int h = 0; h < HEADS; ++h) {
        m[h] = -1e30f; den[h] = 0.f;
        #pragma unroll
        for (int d = 0; d < 8; ++d) num2[h][d] = (f2)0.f;
    }

    const int obase = chunk * OCHUNK + og * 64;
    const f2 zero2 = (f2)0.f;

    for (int r = 0; r < 8; ++r) {
        const int oslice = obase + r * 8;
        // wave-private restage of 8 o's of oc, vv (no barrier: private region)
        {
            const float4* osrc = (const float4*)(oc + (size_t)oslice * LAT);
            const float4* vsrc = (const float4*)(vv + (size_t)oslice * LAT);
            #pragma unroll
            for (int k = 0; k < 2; ++k) {
                *(float4*)&smem[OCB + og * 512 + (ql + 64 * k) * 4] = osrc[ql + 64 * k];
                *(float4*)&smem[VVB + og * 512 + (ql + 64 * k) * 4] = vsrc[ql + 64 * k];
            }
        }

        // distances + rbf for 8 o's (pos_obs loads are wave-uniform -> s_load)
        float d2[8], rbf[8];
        #pragma unroll
        for (int oi = 0; oi < 8; ++oi) {
            const float* po = pos_obs + (size_t)(oslice + oi) * 3;
            float r0 = qp0 - po[0], r1 = qp1 - po[1], r2 = qp2 - po[2];
            d2[oi] = fmaf(r0, r0, fmaf(r1, r1, r2 * r2));
            rbf[oi] = __expf(-d2[oi]);
        }
        f2 lg01[8], lg23[8];
        #pragma unroll
        for (int oi = 0; oi < 8; ++oi) {
            float t = -d2[oi] * inv2s2l;
            f2 ts = (f2){t, t};
            lg01[oi] = (f2){b2l0, b2l1} + ts;
            lg23[oi] = (f2){b2l2, b2l3} + ts;
        }

        // ---- hidden layer, packed fp32: 4 j per j4 pass, 8 o's ----
        #pragma unroll 4
        for (int j4 = 0; j4 < 16; ++j4) {
            // wave-uniform operands
            f4 w2r0 = *(const f4*)&smem[W2B + (j4 * 4 + 0) * 4];
            f4 w2r1 = *(const f4*)&smem[W2B + (j4 * 4 + 1) * 4];
            f4 w2r2 = *(const f4*)&smem[W2B + (j4 * 4 + 2) * 4];
            f4 w2r3 = *(const f4*)&smem[W2B + (j4 * 4 + 3) * 4];
            f4 c9v  = *(const f4*)&smem[C9B + j4 * 4];
            f2 c01 = (f2){c9v.x, c9v.y}, c23 = (f2){c9v.z, c9v.w};
            // per-lane qc pair reads (stride 66 keeps 8B alignment)
            f2 qv01 = *(const f2*)&smem[QCB + ql * 66 + j4 * 4];
            f2 qv23 = *(const f2*)&smem[QCB + ql * 66 + j4 * 4 + 2];

            #pragma unroll
            for (int oi = 0; oi < 8; ++oi) {
                f4 ocv = *(const f4*)&smem[OCB + og * 512 + oi * 64 + j4 * 4];
                f2 rb2 = (f2){rbf[oi], rbf[oi]};
                // j-pair 0: j = 4*j4, 4*j4+1
                f2 hp0 = (qv01 + (f2){ocv.x, ocv.y}) + rb2 * c01;
                hp0 = __builtin_elementwise_max(hp0, zero2);
                f2 hx0 = (f2){hp0.x, hp0.x}, hy0 = (f2){hp0.y, hp0.y};
                lg01[oi] += hx0 * (f2){w2r0.x, w2r0.y};
                lg23[oi] += hx0 * (f2){w2r0.z, w2r0.w};
                lg01[oi] += hy0 * (f2){w2r1.x, w2r1.y};
                lg23[oi] += hy0 * (f2){w2r1.z, w2r1.w};
                // j-pair 1: j = 4*j4+2, 4*j4+3
                f2 hp1 = (qv23 + (f2){ocv.z, ocv.w}) + rb2 * c23;
                hp1 = __builtin_elementwise_max(hp1, zero2);
                f2 hx1 = (f2){hp1.x, hp1.x}, hy1 = (f2){hp1.y, hp1.y};
                lg01[oi] += hx1 * (f2){w2r2.x, w2r2.y};
                lg23[oi] += hx1 * (f2){w2r2.z, w2r2.w};
                lg01[oi] += hy1 * (f2){w2r3.x, w2r3.y};
                lg23[oi] += hy1 * (f2){w2r3.z, w2r3.w};
            }
        }

        // ---- online softmax + packed PV over the 8 o's ----
        #pragma unroll
        for (int oi = 0; oi < 8; ++oi) {
            const int vb = VVB + og * 512 + oi * 64;
            float l[HEADS] = {lg01[oi].x, lg01[oi].y, lg23[oi].x, lg23[oi].y};
            bool up = (l[0] > m[0]) || (l[1] > m[1]) || (l[2] > m[2]) || (l[3] > m[3]);
            if (!__any(up)) {
                #pragma unroll
                for (int h = 0; h < HEADS; ++h) {
                    float p = exp2f(l[h] - m[h]);
                    den[h] += p;
                    f2 p2 = (f2){p, p};
                    #pragma unroll
                    for (int d4 = 0; d4 < 4; ++d4) {
                        f4 t = *(const f4*)&smem[vb + h * HD + d4 * 4];
                        num2[h][d4 * 2 + 0] += p2 * (f2){t.x, t.y};
                        num2[h][d4 * 2 + 1] += p2 * (f2){t.z, t.w};
                    }
                }
            } else {
                #pragma unroll
                for (int h = 0; h < HEADS; ++h) {
                    float nm = fmaxf(m[h], l[h]);
                    float sc = exp2f(m[h] - nm);
                    float p  = exp2f(l[h] - nm);
                    m[h] = nm;
                    den[h] = fmaf(den[h], sc, p);
                    f2 p2 = (f2){p, p};
                    f2 sc2 = (f2){sc, sc};
                    #pragma unroll
                    for (int d4 = 0; d4 < 4; ++d4) {
                        f4 t = *(const f4*)&smem[vb + h * HD + d4 * 4];
                        num2[h][d4 * 2 + 0] = num2[h][d4 * 2 + 0] * sc2 + p2 * (f2){t.x, t.y};
                        num2[h][d4 * 2 + 1] = num2[h][d4 * 2 + 1] * sc2 + p2 * (f2){t.z, t.w};
                    }
                }
            }
        }
    }

    // ---- combine the 4 o-groups at the true chunk max ----
    #pragma unroll
    for (int h = 0; h < HEADS; ++h) smem[LMB + (og * 64 + ql) * 4 + h] = m[h];
    __syncthreads();
    #pragma unroll
    for (int h = 0; h < HEADS; ++h) {
        const float mc = fmaxf(
            fmaxf(smem[LMB + (0 * 64 + ql) * 4 + h], smem[LMB + (1 * 64 + ql) * 4 + h]),
            fmaxf(smem[LMB + (2 * 64 + ql) * 4 + h], smem[LMB + (3 * 64 + ql) * 4 + h]));
        const float sc = exp2f(m[h] - mc);
        den[h] *= sc;
        f2 sc2 = (f2){sc, sc};
        #pragma unroll
        for (int d = 0; d < 8; ++d) num2[h][d] *= sc2;
    }
    __syncthreads();  // all qc reads done before aliasing acc region
    // staged accumulation into acc region (aliases qc region)
    for (int g = 0; g < 4; ++g) {
        if (og == g) {
            if (g == 0) {
                #pragma unroll
                for (int h = 0; h < HEADS; ++h) {
                    smem[QCB + ql * 68 + 64 + h] = den[h];
                    #pragma unroll
                    for (int d = 0; d < 8; ++d)
                        *(f2*)&smem[QCB + ql * 68 + h * HD + d * 2] = num2[h][d];
                }
            } else {
                #pragma unroll
                for (int h = 0; h < HEADS; ++h) {
                    smem[QCB + ql * 68 + 64 + h] += den[h];
                    #pragma unroll
                    for (int d = 0; d < 8; ++d) {
                        f2 cur = *(const f2*)&smem[QCB + ql * 68 + h * HD + d * 2];
                        *(f2*)&smem[QCB + ql * 68 + h * HD + d * 2] = cur + num2[h][d];
                    }
                }
            }
        }
        __syncthreads();
    }
    float* dst = part + (size_t)(chunk * N_Q + qtile * 64) * 68;
    for (int f = tid; f < 64 * 68; f += 256) {
        int qq = f / 68, e = f % 68;
        dst[(size_t)qq * 68 + e] = smem[QCB + qq * 68 + e];
    }
}

// ---- finalize: sum chunk partials, divide ----
__global__ __launch_bounds__(256) void finalize_k(
    const float* __restrict__ part, float* __restrict__ out)
{
    int gid = blockIdx.x * 256 + threadIdx.x;
    int q = gid >> 6, e = gid & 63;
    int h = e >> 4;
    float ns = 0.f, ds = 0.f;
    #pragma unroll
    for (int c = 0; c < NCHUNK; ++c) {
        const float* row = part + (size_t)(c * N_Q + q) * 68;
        ns += row[e];
        ds += row[64 + h];
    }
    out[q * LAT + e] = ns / (ds + 1e-9f);
}

extern "C" void kernel_launch(void* const* d_in, const int* in_sizes, int n_in,
                              void* d_out, int out_size, void* d_ws, size_t ws_size,
                              hipStream_t stream) {
    const float* h_obs     = (const float*)d_in[0];
    const float* pos_obs   = (const float*)d_in[1];
    const float* pos_query = (const float*)d_in[2];
    const float* W1        = (const float*)d_in[3];
    const float* b1        = (const float*)d_in[4];
    const float* W2        = (const float*)d_in[5];
    const float* b2        = (const float*)d_in[6];
    const float* Wv        = (const float*)d_in[7];
    const float* bv        = (const float*)d_in[8];
    const float* log_sigma = (const float*)d_in[9];
    float* out = (float*)d_out;

    float* w   = (float*)d_ws;
    float* qc  = w;                       // 4096*64
    float* oc  = qc + N_Q * LAT;          // 4096*64
    float* vv  = oc + (size_t)N_O * LAT;  // 4096*64
    float* part = vv + (size_t)N_O * LAT; // 16*4096*68

    prep_all<<<(N_Q + N_O + N_O) * LAT / 256, 256, 0, stream>>>(
        h_obs, pos_obs, pos_query, W1, b1, Wv, bv, qc, oc, vv);
    attn_chunk<<<dim3(NCHUNK, N_Q / 64), 256, 0, stream>>>(
        pos_obs, pos_query, W1, W2, b2, log_sigma, qc, oc, vv, part);
    finalize_k<<<N_Q * LAT / 256, 256, 0, stream>>>(part, out);
}